// Round 7
// baseline (52.186 us; speedup 1.0000x reference)
//
#include <hip/hip_runtime.h>

// out[t*768 + e] = weight[e*VOCAB + x[t]]
// memset(cur) -> scatter tokens into fixed-cap per-window buckets (64-col
// windows, cap 80, mean 20.8; overflow -> spill list) -> gather: one block per
// (window, 128-row group) stages 128x64 f32 slab to LDS (coalesced float4,
// pad-65 => conflict-free serve) and writes each bucket token's rows with
// 256B-coalesced nontemporal stores; blocks 0..63 then drain the spill list
// (no-op unless adversarial input overflowed a bucket).

#define VOCAB 50257
#define EMBED 768
#define WINB 64
#define NWIN 786           // ceil(VOCAB/64); last window has 17 valid cols
#define RG 6               // row groups
#define ROWS 128           // EMBED / RG
#define LSTRIDE 65         // +1 pad -> serve reads bank=(r+c)%32, 2-way free
#define CAP 80             // bucket capacity (mean load 20.8)

__device__ __forceinline__ int xcd_swizzle(int bid, int nwg) {
  const int NX = 8;                   // bijective m204 variant
  int q = nwg / NX, r = nwg % NX;
  int xcd = bid % NX, idx = bid / NX;
  int base = (xcd < r) ? xcd * (q + 1) : r * (q + 1) + (xcd - r) * q;
  return base + idx;
}

__global__ __launch_bounds__(256) void scatter_kernel(const int* __restrict__ x,
                                                      int* __restrict__ cur,
                                                      int* __restrict__ buckets,
                                                      int* __restrict__ spill_cnt,
                                                      int* __restrict__ spill,
                                                      int n) {
  int i = blockIdx.x * blockDim.x + threadIdx.x;
  if (i < n) {
    int v = x[i];
    int win = v >> 6;
    int p = atomicAdd(&cur[win], 1);
    if (p < CAP) {
      buckets[win * CAP + p] = (i << 6) | (v & 63);
    } else {
      int s = atomicAdd(spill_cnt, 1);
      spill[s] = (i << 16) | v;       // t:14b | v:16b
    }
  }
}

__global__ __launch_bounds__(256) void gather_kernel(const float* __restrict__ w,
                                                     const int* __restrict__ cur,
                                                     const int* __restrict__ buckets,
                                                     const int* __restrict__ spill_cnt,
                                                     const int* __restrict__ spill,
                                                     float* __restrict__ out) {
  __shared__ float lds[ROWS * LSTRIDE];   // 33.3 KB
  __shared__ int toks[CAP];
  const int logical = xcd_swizzle(blockIdx.x, NWIN * RG);
  const int wid = logical % NWIN;     // adjacent wids share an XCD chunk
  const int rg  = logical / NWIN;
  const int row0 = rg * ROWS;
  const int col0 = wid * WINB;
  const int tid = threadIdx.x;
  const int wave = tid >> 6, lane = tid & 63;

  int m = cur[wid];                   // uniform scalar load
  if (m > CAP) m = CAP;

  // token list: single conditional load, overlaps staging
  if (tid < m) toks[tid] = buckets[wid * CAP + tid];

  // --- stage 128x64 slab, coalesced float4 (8 per thread) ---
  if (wid != NWIN - 1) {
    #pragma unroll
    for (int j = tid; j < ROWS * 16; j += 256) {
      int r = j >> 4, c4 = (j & 15) << 2;
      float4 v = *(const float4*)&w[(size_t)(row0 + r) * VOCAB + col0 + c4];
      float* d = &lds[r * LSTRIDE + c4];
      d[0] = v.x; d[1] = v.y; d[2] = v.z; d[3] = v.w;
    }
  } else {
    for (int j = tid; j < ROWS * 16; j += 256) {
      int r = j >> 4, c4 = (j & 15) << 2;
      float* d = &lds[r * LSTRIDE + c4];
      for (int u = 0; u < 4; ++u) {
        int c = col0 + c4 + u;
        d[u] = (c < VOCAB) ? w[(size_t)(row0 + r) * VOCAB + c] : 0.f;
      }
    }
  }
  __syncthreads();

  // --- serve bucket tokens from LDS; nontemporal 256B-coalesced stores ---
  for (int i = wave; i < m; i += 4) {
    int pk = toks[i];                 // LDS broadcast
    int t = pk >> 6, c = pk & 63;
    float* o = &out[(size_t)t * EMBED + row0];
    #pragma unroll
    for (int k = 0; k < 2; ++k)
      __builtin_nontemporal_store(lds[(k * 64 + lane) * LSTRIDE + c],
                                  &o[k * 64 + lane]);
  }

  // --- adversarial-only spill drain (spill_cnt==0 on random data) ---
  if (blockIdx.x < 64) {
    int cnt = *spill_cnt;
    for (int s = blockIdx.x; s < cnt; s += 64) {
      int pk = spill[s];
      int t = pk >> 16, v = pk & 0xFFFF;
      for (int e = tid; e < EMBED; e += 256)
        out[(size_t)t * EMBED + e] = w[(size_t)e * VOCAB + v];
    }
  }
}

extern "C" void kernel_launch(void* const* d_in, const int* in_sizes, int n_in,
                              void* d_out, int out_size, void* d_ws, size_t ws_size,
                              hipStream_t stream) {
  const int*   x = (const int*)d_in[0];
  const float* w = (const float*)d_in[1];
  float* out = (float*)d_out;
  const int n = in_sizes[0];          // 16384 tokens

  int* cur       = (int*)d_ws;             // [NWIN]
  int* spill_cnt = cur + NWIN;             // [1] (contiguous with cur for memset)
  int* spill     = spill_cnt + 1;          // [n]
  int* buckets   = spill + n;              // [NWIN*CAP]

  hipMemsetAsync(cur, 0, (NWIN + 1) * sizeof(int), stream);
  scatter_kernel<<<(n + 255) / 256, 256, 0, stream>>>(x, cur, buckets,
                                                      spill_cnt, spill, n);
  gather_kernel<<<NWIN * RG, 256, 0, stream>>>(w, cur, buckets,
                                               spill_cnt, spill, out);
}

// Round 8
// 46.781 us; speedup vs baseline: 1.1155x; 1.1155x over previous
//
#include <hip/hip_runtime.h>

// out[t*768 + e] = weight[e*VOCAB + x[t]]
// memset(cur+spill_cnt) -> scatter tokens into fixed-cap per-window buckets
// (32-col windows, cap 64, mean 10.4; overflow -> spill list) -> gather:
// one block per (window, 96-row group) stages the 96x32 f32 slab to LDS
// (float4 global loads + single ds_write_b128 per granule; LSTRIDE=36 keeps
// rows 16B-aligned), then serves bucket tokens with 256B-coalesced
// nontemporal stores. Blocks 0..63 drain the spill list (no-op on random
// data). RG=8 -> grid 12568 = 8*1571: each XCD owns one row group = a
// contiguous 19MB weight slice; adjacent wids adjacent in time on the XCD.

#define VOCAB 50257
#define EMBED 768
#define WINB 32
#define NWIN 1571          // ceil(VOCAB/32)
#define RG 8               // row groups; rg == XCD id (grid = 8*NWIN)
#define ROWS 96            // EMBED / RG
#define LSTRIDE 36         // 144B rows: 16B-aligned -> ds_write_b128 staging
#define CAP 64             // bucket capacity (mean load 10.4)

__device__ __forceinline__ int xcd_swizzle(int bid, int nwg) {
  const int NX = 8;                   // bijective (nwg % 8 == 0 here)
  int q = nwg / NX;
  int xcd = bid % NX, idx = bid / NX;
  return xcd * q + idx;
}

__global__ __launch_bounds__(256) void scatter_kernel(const int* __restrict__ x,
                                                      int* __restrict__ cur,
                                                      int* __restrict__ buckets,
                                                      int* __restrict__ spill_cnt,
                                                      int* __restrict__ spill,
                                                      int n) {
  int i = blockIdx.x * blockDim.x + threadIdx.x;
  if (i < n) {
    int v = x[i];
    int win = v >> 5;
    int p = atomicAdd(&cur[win], 1);
    if (p < CAP) {
      buckets[win * CAP + p] = (i << 5) | (v & 31);
    } else {
      int s = atomicAdd(spill_cnt, 1);
      spill[s] = (i << 16) | v;       // t:14b | v:16b
    }
  }
}

__global__ __launch_bounds__(256) void gather_kernel(const float* __restrict__ w,
                                                     const int* __restrict__ cur,
                                                     const int* __restrict__ buckets,
                                                     const int* __restrict__ spill_cnt,
                                                     const int* __restrict__ spill,
                                                     float* __restrict__ out) {
  __shared__ float lds[ROWS * LSTRIDE];   // 13.8 KB
  __shared__ int toks[CAP];
  const int logical = xcd_swizzle(blockIdx.x, NWIN * RG);
  const int wid = logical % NWIN;     // fastest within an XCD chunk
  const int rg  = logical / NWIN;     // == XCD id
  const int row0 = rg * ROWS;
  const int col0 = wid * WINB;
  const int tid = threadIdx.x;
  const int wave = tid >> 6, lane = tid & 63;

  int m = cur[wid];                   // uniform scalar load
  if (m > CAP) m = CAP;

  // token list: single conditional load, overlaps staging
  if (tid < m) toks[tid] = buckets[wid * CAP + tid];

  // --- stage 96x32 slab: 3 granules/thread, one b128 LDS write each ---
  if (wid != NWIN - 1) {
    #pragma unroll
    for (int k = 0; k < 3; ++k) {
      int j = k * 256 + tid;
      int r = j >> 3, g = j & 7;      // row, 16B-granule
      float4 v = *(const float4*)&w[(size_t)(row0 + r) * VOCAB + col0 + (g << 2)];
      *(float4*)&lds[r * LSTRIDE + (g << 2)] = v;   // 16B-aligned
    }
  } else {
    for (int k = 0; k < 3; ++k) {
      int j = k * 256 + tid;
      int r = j >> 3, g = j & 7;
      float4 v;
      float* pv = (float*)&v;
      for (int u = 0; u < 4; ++u) {
        int c = col0 + (g << 2) + u;
        pv[u] = (c < VOCAB) ? w[(size_t)(row0 + r) * VOCAB + c] : 0.f;
      }
      *(float4*)&lds[r * LSTRIDE + (g << 2)] = v;
    }
  }
  __syncthreads();

  // --- serve bucket tokens; 256B-coalesced nontemporal stores ---
  for (int i = wave; i < m; i += 4) {
    int pk = toks[i];                 // LDS broadcast
    int t = pk >> 5, c = pk & 31;
    float* o = &out[(size_t)t * EMBED + row0];
    __builtin_nontemporal_store(lds[lane * LSTRIDE + c], &o[lane]);
    if (lane < ROWS - 64)
      __builtin_nontemporal_store(lds[(64 + lane) * LSTRIDE + c], &o[64 + lane]);
  }

  // --- adversarial-only spill drain (spill_cnt==0 on random data) ---
  if (blockIdx.x < 64) {
    int cnt = *spill_cnt;
    for (int s = blockIdx.x; s < cnt; s += 64) {
      int pk = spill[s];
      int t = pk >> 16, v = pk & 0xFFFF;
      for (int e = tid; e < EMBED; e += 256)
        out[(size_t)t * EMBED + e] = w[(size_t)e * VOCAB + v];
    }
  }
}

extern "C" void kernel_launch(void* const* d_in, const int* in_sizes, int n_in,
                              void* d_out, int out_size, void* d_ws, size_t ws_size,
                              hipStream_t stream) {
  const int*   x = (const int*)d_in[0];
  const float* w = (const float*)d_in[1];
  float* out = (float*)d_out;
  const int n = in_sizes[0];          // 16384 tokens

  int* cur       = (int*)d_ws;             // [NWIN]
  int* spill_cnt = cur + NWIN;             // [1] (contiguous for one memset)
  int* spill     = spill_cnt + 1;          // [n]
  int* buckets   = spill + n;              // [NWIN*CAP]

  hipMemsetAsync(cur, 0, (NWIN + 1) * sizeof(int), stream);
  scatter_kernel<<<(n + 255) / 256, 256, 0, stream>>>(x, cur, buckets,
                                                      spill_cnt, spill, n);
  gather_kernel<<<NWIN * RG, 256, 0, stream>>>(w, cur, buckets,
                                               spill_cnt, spill, out);
}

// Round 10
// 45.950 us; speedup vs baseline: 1.1357x; 1.0181x over previous
//
#include <hip/hip_runtime.h>

// out[t*768 + e] = weight[e*VOCAB + x[t]]
// memset(cur+spill_cnt) -> scatter tokens into fixed-cap per-window buckets
// (32-col windows, cap 64, mean 10.4; overflow -> spill list) -> persistent
// gather (grid 2048 = 8 blocks/CU): block b owns XCD slice rows
// [(b&7)*96, +96) and wids {b>>3 + 256k}. Per tile: commit prefetched 96x32
// f32 slab (regs -> ds_write_b128; LSTRIDE=36 keeps rows 16B-aligned), issue
// next tile's global loads (HBM latency hides under serve), serve bucket
// tokens with 256B-coalesced nontemporal stores. Blocks 0..63 drain the
// spill list first (no-op on random data).

#define VOCAB 50257
#define EMBED 768
#define WINB 32
#define NWIN 1571          // ceil(VOCAB/32)
#define ROWS 96            // EMBED / 8; row group == XCD id (b&7)
#define LSTRIDE 36         // 144B rows: 16B-aligned -> single ds_write_b128
#define CAP 64             // bucket capacity (mean load 10.4)
#define NBLK 2048          // 8 blocks/CU x 256 CU
#define NPX 256            // blocks per XCD

__global__ __launch_bounds__(256) void scatter_kernel(const int* __restrict__ x,
                                                      int* __restrict__ cur,
                                                      int* __restrict__ buckets,
                                                      int* __restrict__ spill_cnt,
                                                      int* __restrict__ spill,
                                                      int n) {
  int i = blockIdx.x * blockDim.x + threadIdx.x;
  if (i < n) {
    int v = x[i];
    int win = v >> 5;
    int p = atomicAdd(&cur[win], 1);
    if (p < CAP) {
      buckets[win * CAP + p] = (i << 5) | (v & 31);
    } else {
      int s = atomicAdd(spill_cnt, 1);
      spill[s] = (i << 16) | v;       // t:14b | v:16b
    }
  }
}

__global__ __launch_bounds__(256) void gather_kernel(const float* __restrict__ w,
                                                     const int* __restrict__ cur,
                                                     const int* __restrict__ buckets,
                                                     const int* __restrict__ spill_cnt,
                                                     const int* __restrict__ spill,
                                                     float* __restrict__ out) {
  __shared__ float lds[ROWS * LSTRIDE];   // 13.8 KB
  __shared__ int toks[CAP];
  const int tid = threadIdx.x;
  const int b = blockIdx.x;

  // --- adversarial-only spill drain (spill_cnt==0 on random data) ---
  if (b < 64) {
    int cnt = *spill_cnt;
    for (int s = b; s < cnt; s += 64) {
      int pk = spill[s];
      int t = pk >> 16, v = pk & 0xFFFF;
      for (int e = tid; e < EMBED; e += 256)
        out[(size_t)t * EMBED + e] = w[(size_t)e * VOCAB + v];
    }
  }

  // --- persistent tile loop with cross-tile register prefetch ---
  const int xcd = b & 7, s0 = b >> 3;
  const int row0 = xcd * ROWS;        // XCD owns a contiguous 19MB row slice
  const int wave = tid >> 6, lane = tid & 63;
  const int rr = tid >> 3, g4 = (tid & 7) << 2;

  float4 pf0, pf1, pf2;               // prefetched slab granules
  int ptk = 0, pcnt = 0;              // prefetched token word + bucket count

  auto issue = [&](int wid) {
    const float* base = w + (size_t)(row0 + rr) * VOCAB + wid * WINB + g4;
    if (wid != NWIN - 1) {
      pf0 = *(const float4*)(base);
      pf1 = *(const float4*)(base + (size_t)32 * VOCAB);
      pf2 = *(const float4*)(base + (size_t)64 * VOCAB);
    } else {
      float* p0 = (float*)&pf0; float* p1 = (float*)&pf1; float* p2 = (float*)&pf2;
      for (int u = 0; u < 4; ++u) {
        bool ok = wid * WINB + g4 + u < VOCAB;
        p0[u] = ok ? base[u] : 0.f;
        p1[u] = ok ? base[(size_t)32 * VOCAB + u] : 0.f;
        p2[u] = ok ? base[(size_t)64 * VOCAB + u] : 0.f;
      }
    }
    if (tid < CAP) ptk = buckets[wid * CAP + tid];
    pcnt = cur[wid];                  // uniform
  };

  issue(s0);                          // s0 < 256 <= NWIN always
  for (int m = s0; m < NWIN; m += NPX) {
    __syncthreads();                  // previous serve done with lds/toks
    *(float4*)&lds[rr * LSTRIDE + g4] = pf0;           // 16B-aligned b128
    *(float4*)&lds[(rr + 32) * LSTRIDE + g4] = pf1;
    *(float4*)&lds[(rr + 64) * LSTRIDE + g4] = pf2;
    if (tid < CAP) toks[tid] = ptk;
    int mcnt = pcnt > CAP ? CAP : pcnt;
    int mn = m + NPX;
    if (mn < NWIN) issue(mn);         // next tile's loads fly under serve
    __syncthreads();

    for (int i = wave; i < mcnt; i += 4) {
      int pk = toks[i];               // LDS broadcast
      int t = pk >> 5, c = pk & 31;
      float* o = &out[(size_t)t * EMBED + row0];
      __builtin_nontemporal_store(lds[lane * LSTRIDE + c], &o[lane]);
      if (lane < ROWS - 64)
        __builtin_nontemporal_store(lds[(64 + lane) * LSTRIDE + c], &o[64 + lane]);
    }
  }
}

extern "C" void kernel_launch(void* const* d_in, const int* in_sizes, int n_in,
                              void* d_out, int out_size, void* d_ws, size_t ws_size,
                              hipStream_t stream) {
  const int*   x = (const int*)d_in[0];
  const float* w = (const float*)d_in[1];
  float* out = (float*)d_out;
  const int n = in_sizes[0];          // 16384 tokens

  int* cur       = (int*)d_ws;        // [NWIN]
  int* spill_cnt = cur + NWIN;        // [1] (contiguous with cur for memset)
  int* spill     = spill_cnt + 1;     // [n]
  int* buckets   = spill + n;         // [NWIN*CAP]

  hipMemsetAsync(cur, 0, (NWIN + 1) * sizeof(int), stream);
  scatter_kernel<<<(n + 255) / 256, 256, 0, stream>>>(x, cur, buckets,
                                                      spill_cnt, spill, n);
  gather_kernel<<<NBLK, 256, 0, stream>>>(w, cur, buckets,
                                          spill_cnt, spill, out);
}